// Round 1
// baseline (1130.003 us; speedup 1.0000x reference)
//
#include <hip/hip_runtime.h>
#include <stdint.h>

// Problem constants (from reference setup_inputs)
#define N_NODES 25000
#define N_EDGES 400000
// N=2, IN_DIM=64, HEADS=4, HEAD_DIM=16 -> 128 floats per node/edge, 64 cols out per n

// Float atomic max via sign-split trick:
//  - non-negative floats are monotone as signed ints  -> atomicMax(int)
//  - negative floats are reverse-monotone as uints    -> atomicMin(uint)
// Init value is -inf (0xFF800000): signed int = very negative (any >=0 wins),
// uint = very large (any negative float's uint is smaller -> wins).
__device__ __forceinline__ void atomicMaxF(float* addr, float val) {
    if (val == 0.0f) val = 0.0f;   // canonicalize -0.0 -> +0.0 (int repr 0, not INT_MIN)
    if (val >= 0.0f) {
        atomicMax((int*)addr, __float_as_int(val));
    } else {
        atomicMin((unsigned int*)addr, __float_as_uint(val));
    }
}

// out has 3,200,000 floats = 800,000 float4; 800000/256 = 3125 blocks exactly.
__global__ __launch_bounds__(256) void init_out_kernel(float4* __restrict__ out) {
    const int i = blockIdx.x * 256 + threadIdx.x;
    const float f = __uint_as_float(0xFF800000u);   // -inf
    out[i] = make_float4(f, f, f, f);
}

__global__ __launch_bounds__(256) void finalize_kernel(float4* __restrict__ out) {
    const int i = blockIdx.x * 256 + threadIdx.x;
    float4 v = out[i];
    v.x = (__float_as_uint(v.x) == 0xFF800000u) ? 0.0f : v.x;
    v.y = (__float_as_uint(v.y) == 0xFF800000u) ? 0.0f : v.y;
    v.z = (__float_as_uint(v.z) == 0xFF800000u) ? 0.0f : v.z;
    v.w = (__float_as_uint(v.w) == 0xFF800000u) ? 0.0f : v.w;
    out[i] = v;
}

// Q = h @ W_Q.  h viewed as [50000, 64] row-major; Q same layout.
// 3125 blocks x 256 threads; block handles 16 rows (4 per wave), exact cover.
__global__ __launch_bounds__(256) void q_kernel(
    const float* __restrict__ h, const float* __restrict__ Wq, float* __restrict__ Q)
{
    __shared__ float sW[4096];    // 16 KB, W_Q[i][c] at sW[i*64+c]
    __shared__ float sR[4][64];   // one staged row per wave
    const int t = threadIdx.x;
    for (int i = t; i < 4096; i += 256) sW[i] = Wq[i];
    __syncthreads();
    const int w = t >> 6, l = t & 63;
    for (int r = 0; r < 4; ++r) {
        const int row = blockIdx.x * 16 + w * 4 + r;   // < 50000 always
        const float a = h[row * 64 + l];
        __syncthreads();          // uniform; fences prior iter's reads of sR[w]
        sR[w][l] = a;
        __syncthreads();
        float acc = 0.0f;
        #pragma unroll
        for (int i = 0; i < 64; ++i) acc = fmaf(sR[w][i], sW[i * 64 + l], acc);
        Q[row * 64 + l] = acc;
    }
}

// Edge kernel: 12500 blocks x 256 threads (4 waves).
// wave w handles (edge_pair_offset = w>>1, n = w&1); lane l = output column.
// Block loops 16 iterations x 2 edges = 32 edges; 12500*32 = 400000 exactly.
// LDS: W_K/W_V interleaved (b64 reads, 2-way bank alias = free), W_repe scalar,
// per-wave diff/e rows read as broadcast float2.
__global__ __launch_bounds__(256) void edge_kernel(
    const float* __restrict__ h, const float* __restrict__ e,
    const float* __restrict__ Wk, const float* __restrict__ Wv,
    const float* __restrict__ Wr, const float* __restrict__ Q,
    const int* __restrict__ src, const int* __restrict__ dst,
    float* __restrict__ out)
{
    __shared__ float sKV[8192];     // 32 KB: element (i,c) of {K,V} at [2*(i*64+c)]
    __shared__ float sWr[4096];     // 16 KB
    __shared__ float sDE[4][128];   // per-wave (diff, e) interleaved pairs
    const int t = threadIdx.x;
    for (int i = t; i < 4096; i += 256) {
        *(float2*)&sKV[2 * i] = make_float2(Wk[i], Wv[i]);
        sWr[i] = Wr[i];
    }
    __syncthreads();

    const int w = t >> 6, l = t & 63;
    const int n = w & 1, eo = w >> 1;
    const int ebase = blockIdx.x * 32;

    for (int it = 0; it < 16; ++it) {
        const int edge = ebase + it * 2 + eo;
        const int s = src[edge], d = dst[edge];
        const int dbase = (d * 2 + n) * 64;
        const float hs = h[(s * 2 + n) * 64 + l];
        const float hd = h[dbase + l];
        const float ev = e[(edge * 2 + n) * 64 + l];
        const float qv = Q[dbase + l];
        const float df = fmaxf(hs - hd, 0.0f);   // relu(h[src]-h[dst])

        __syncthreads();                          // uniform across waves (16x each)
        *(float2*)&sDE[w][2 * l] = make_float2(df, ev);
        __syncthreads();

        float ak = 0.0f, av = 0.0f, ar = 0.0f;
        #pragma unroll
        for (int i = 0; i < 64; ++i) {
            const float2 de = *(const float2*)&sDE[w][2 * i];       // broadcast
            const float2 kv = *(const float2*)&sKV[i * 128 + 2 * l]; // b64
            const float wr = sWr[i * 64 + l];
            ak = fmaf(de.x, kv.x, ak);
            av = fmaf(de.x, kv.y, av);
            ar = fmaf(de.y, wr, ar);
        }

        // norms over HEAD_DIM=16 contiguous lanes (head = l>>4)
        float sk = ak * ak, sq = qv * qv;
        #pragma unroll
        for (int m = 1; m < 16; m <<= 1) {
            sk += __shfl_xor(sk, m, 64);
            sq += __shfl_xor(sq, m, 64);
        }
        const float scale = sqrtf(sk) * sqrtf(sq) + 1e-6f;
        const float msg = (qv * ak * scale + ar) * av;
        atomicMaxF(&out[dbase + l], msg);
    }
}

extern "C" void kernel_launch(void* const* d_in, const int* in_sizes, int n_in,
                              void* d_out, int out_size, void* d_ws, size_t ws_size,
                              hipStream_t stream) {
    const float* h  = (const float*)d_in[0];
    const float* e  = (const float*)d_in[1];
    const float* Wq = (const float*)d_in[2];
    const float* Wk = (const float*)d_in[3];
    const float* Wv = (const float*)d_in[4];
    const float* Wr = (const float*)d_in[5];
    const int*   src = (const int*)d_in[6];
    const int*   dst = (const int*)d_in[7];
    float* out = (float*)d_out;
    float* Q   = (float*)d_ws;   // 50000*64 floats = 12.8 MB scratch

    init_out_kernel<<<3125, 256, 0, stream>>>((float4*)out);
    q_kernel<<<3125, 256, 0, stream>>>(h, Wq, Q);
    edge_kernel<<<12500, 256, 0, stream>>>(h, e, Wk, Wv, Wr, Q, src, dst, out);
    finalize_kernel<<<3125, 256, 0, stream>>>((float4*)out);
}

// Round 2
// 555.609 us; speedup vs baseline: 2.0338x; 2.0338x over previous
//
#include <hip/hip_runtime.h>
#include <stdint.h>

// Problem constants
#define N_NODES 25000
#define N_EDGES 400000
// N=2, IN_DIM=64, HEADS=4, HEAD_DIM=16; rows = edge*2+n (64 floats each)

typedef __attribute__((ext_vector_type(8))) short short8;   // 8 bf16 = 4 VGPRs
typedef __attribute__((ext_vector_type(4))) float f32x4;    // MFMA accum

#define MFMA16(a, b, c) __builtin_amdgcn_mfma_f32_16x16x32_bf16((a), (b), (c), 0, 0, 0)

// fp32 -> bf16 bits, round-to-nearest-even (inputs are finite; no NaN handling)
__device__ __forceinline__ short bf16r(float x) {
    unsigned u = __float_as_uint(x);
    u += 0x7FFFu + ((u >> 16) & 1u);
    return (short)(u >> 16);
}

// B fragment for cols [colbase, colbase+16) of a [64k x 64n] row-major fp32 W.
// B layout: n = lane&15, k = (lane>>4)*8 + j  (+32 per khalf)
__device__ __forceinline__ short8 load_bfrag(const float* __restrict__ W,
                                             int colbase, int lane, int khalf) {
    const int n = colbase + (lane & 15);
    const int k0 = khalf * 32 + ((lane >> 4) << 3);
    short8 f;
    #pragma unroll
    for (int j = 0; j < 8; ++j) f[j] = bf16r(W[(k0 + j) * 64 + n]);
    return f;
}

// A fragment from LDS tile (rows padded to 72 shorts = 144 B).
// A layout: m = lane&15, k = (lane>>4)*8 + j  (+32 per khalf)
__device__ __forceinline__ short8 afrag(const short* S, int mbase, int lane, int khalf) {
    return *(const short8*)&S[(mbase + (lane & 15)) * 72 + khalf * 32 + ((lane >> 4) << 3)];
}

// float atomic max: >=0 monotone as int -> atomicMax(int); <0 reverse-monotone
// as uint -> atomicMin(uint). Init -inf (0xFF800000) loses to everything.
__device__ __forceinline__ void atomicMaxF(float* addr, float val) {
    if (val == 0.0f) val = 0.0f;   // canonicalize -0.0
    if (val >= 0.0f) atomicMax((int*)addr, __float_as_int(val));
    else             atomicMin((unsigned int*)addr, __float_as_uint(val));
}

// out = 3,200,000 floats = 800,000 float4 ; 3125 blocks x 256
__global__ __launch_bounds__(256) void init_out_kernel(float4* __restrict__ out) {
    const int i = blockIdx.x * 256 + threadIdx.x;
    const float f = __uint_as_float(0xFF800000u);
    out[i] = make_float4(f, f, f, f);
}

__global__ __launch_bounds__(256) void finalize_kernel(float4* __restrict__ out) {
    const int i = blockIdx.x * 256 + threadIdx.x;
    float4 v = out[i];
    v.x = (__float_as_uint(v.x) == 0xFF800000u) ? 0.0f : v.x;
    v.y = (__float_as_uint(v.y) == 0xFF800000u) ? 0.0f : v.y;
    v.z = (__float_as_uint(v.z) == 0xFF800000u) ? 0.0f : v.z;
    v.w = (__float_as_uint(v.w) == 0xFF800000u) ? 0.0f : v.w;
    out[i] = v;
}

// Q = h @ W_Q via MFMA. 782 blocks x 256; block handles 64 rows of [50000,64].
__global__ __launch_bounds__(256) void q_mfma_kernel(
    const float* __restrict__ h, const float* __restrict__ Wq, float* __restrict__ Q)
{
    __shared__ short sH[64 * 72];
    const int t = threadIdx.x;
    const int lane = t & 63, w = t >> 6;
    const int wcol = w << 4;
    const int ln = lane & 15, lq = lane >> 4;
    const int base = blockIdx.x * 64;

    const short8 b0 = load_bfrag(Wq, wcol, lane, 0);
    const short8 b1 = load_bfrag(Wq, wcol, lane, 1);

    {   // stage 64 rows: thread t -> row t>>2, 16-float chunk (t&3)*16
        const int r = t >> 2, c4 = (t & 3) << 4;
        int row = base + r; if (row > 49999) row = 49999;   // tail clamp (loads only)
        const float4* p = (const float4*)&h[row * 64 + c4];
        short tmp[16];
        #pragma unroll
        for (int i = 0; i < 4; ++i) {
            float4 x = p[i];
            tmp[4*i+0] = bf16r(x.x); tmp[4*i+1] = bf16r(x.y);
            tmp[4*i+2] = bf16r(x.z); tmp[4*i+3] = bf16r(x.w);
        }
        *(short8*)&sH[r * 72 + c4]     = *(short8*)&tmp[0];
        *(short8*)&sH[r * 72 + c4 + 8] = *(short8*)&tmp[8];
    }
    __syncthreads();

    #pragma unroll
    for (int m = 0; m < 4; ++m) {
        short8 a0 = afrag(sH, m << 4, lane, 0);
        short8 a1 = afrag(sH, m << 4, lane, 1);
        f32x4 acc = {0.f, 0.f, 0.f, 0.f};
        acc = MFMA16(a0, b0, acc);
        acc = MFMA16(a1, b1, acc);
        #pragma unroll
        for (int reg = 0; reg < 4; ++reg) {
            const int row = base + (m << 4) + (lq << 2) + reg;  // C: row=quad*4+reg
            if (row < 50000) Q[row * 64 + wcol + ln] = acc[reg]; // C: col=lane&15
        }
    }
}

// Edge kernel: 2500 blocks x 5 tiles x 32 edges = 400000 exactly.
// Per tile: 64 A-rows (edge,n); wave w = head w's 16 output cols for all rows.
#define TILES_PER_BLOCK 5
__global__ __launch_bounds__(256) void edge_mfma_kernel(
    const float* __restrict__ h, const float* __restrict__ e,
    const float* __restrict__ Wk, const float* __restrict__ Wv,
    const float* __restrict__ Wr, const float* __restrict__ Q,
    const int* __restrict__ src, const int* __restrict__ dst,
    float* __restrict__ out)
{
    __shared__ short sD[64 * 72];   // diff tile, 144 B rows (pad kills b128 clumping)
    __shared__ short sE[64 * 72];   // e tile
    const int t = threadIdx.x;
    const int lane = t & 63, w = t >> 6;
    const int wcol = w << 4;
    const int ln = lane & 15, lq = lane >> 4;

    // weights resident in registers for the whole block (one head-slab per wave)
    const short8 bK0 = load_bfrag(Wk, wcol, lane, 0);
    const short8 bK1 = load_bfrag(Wk, wcol, lane, 1);
    const short8 bV0 = load_bfrag(Wv, wcol, lane, 0);
    const short8 bV1 = load_bfrag(Wv, wcol, lane, 1);
    const short8 bR0 = load_bfrag(Wr, wcol, lane, 0);
    const short8 bR1 = load_bfrag(Wr, wcol, lane, 1);

    const int r = t >> 2, c4 = (t & 3) << 4;   // staging: row r, 16-float chunk

    for (int it = 0; it < TILES_PER_BLOCK; ++it) {
        const int ebase = (blockIdx.x * TILES_PER_BLOCK + it) << 5;

        {   // stage e rows (contiguous: 16 KB stream)
            const float4* pe = (const float4*)e + ((size_t)ebase << 5) + (t << 2);
            short tmp[16];
            #pragma unroll
            for (int i = 0; i < 4; ++i) {
                float4 x = pe[i];
                tmp[4*i+0] = bf16r(x.x); tmp[4*i+1] = bf16r(x.y);
                tmp[4*i+2] = bf16r(x.z); tmp[4*i+3] = bf16r(x.w);
            }
            *(short8*)&sE[r * 72 + c4]     = *(short8*)&tmp[0];
            *(short8*)&sE[r * 72 + c4 + 8] = *(short8*)&tmp[8];
        }
        {   // stage diff = relu(h[src]-h[dst]) rows (gathered)
            const int edge = ebase + (r >> 1);
            const int s = src[edge], d = dst[edge];
            const float4* ps = (const float4*)&h[(((s << 1) + (r & 1)) << 6) + c4];
            const float4* pd = (const float4*)&h[(((d << 1) + (r & 1)) << 6) + c4];
            short tmp[16];
            #pragma unroll
            for (int i = 0; i < 4; ++i) {
                float4 x = ps[i], y = pd[i];
                tmp[4*i+0] = bf16r(fmaxf(x.x - y.x, 0.f));
                tmp[4*i+1] = bf16r(fmaxf(x.y - y.y, 0.f));
                tmp[4*i+2] = bf16r(fmaxf(x.z - y.z, 0.f));
                tmp[4*i+3] = bf16r(fmaxf(x.w - y.w, 0.f));
            }
            *(short8*)&sD[r * 72 + c4]     = *(short8*)&tmp[0];
            *(short8*)&sD[r * 72 + c4 + 8] = *(short8*)&tmp[8];
        }
        __syncthreads();

        #pragma unroll
        for (int m = 0; m < 4; ++m) {
            short8 a0 = afrag(sD, m << 4, lane, 0);
            short8 a1 = afrag(sD, m << 4, lane, 1);
            short8 g0 = afrag(sE, m << 4, lane, 0);
            short8 g1 = afrag(sE, m << 4, lane, 1);
            f32x4 aK = {0.f,0.f,0.f,0.f}, aV = aK, aR = aK;
            aK = MFMA16(a0, bK0, aK); aK = MFMA16(a1, bK1, aK);
            aV = MFMA16(a0, bV0, aV); aV = MFMA16(a1, bV1, aV);
            aR = MFMA16(g0, bR0, aR); aR = MFMA16(g1, bR1, aR);

            #pragma unroll
            for (int reg = 0; reg < 4; ++reg) {
                const int rl = (m << 4) + (lq << 2) + reg;   // local A-row
                const int edge2 = ebase + (rl >> 1);
                const int d2 = dst[edge2];                   // broadcast in 16-group
                const int rowbase = (((d2 << 1) + (rl & 1)) << 6);
                const float qv = Q[rowbase + wcol + ln];
                // norms over the head's 16 cols = 16-lane reduction (bits 0-3)
                float sk = aK[reg] * aK[reg];
                float sq = qv * qv;
                sk += __shfl_xor(sk, 1);  sq += __shfl_xor(sq, 1);
                sk += __shfl_xor(sk, 2);  sq += __shfl_xor(sq, 2);
                sk += __shfl_xor(sk, 4);  sq += __shfl_xor(sq, 4);
                sk += __shfl_xor(sk, 8);  sq += __shfl_xor(sq, 8);
                const float scale = sqrtf(sk) * sqrtf(sq) + 1e-6f;
                const float msg = (qv * aK[reg] * scale + aR[reg]) * aV[reg];
                atomicMaxF(&out[rowbase + wcol + ln], msg);
            }
        }
        __syncthreads();   // protect sD/sE before next tile's staging
    }
}

extern "C" void kernel_launch(void* const* d_in, const int* in_sizes, int n_in,
                              void* d_out, int out_size, void* d_ws, size_t ws_size,
                              hipStream_t stream) {
    const float* h  = (const float*)d_in[0];
    const float* e  = (const float*)d_in[1];
    const float* Wq = (const float*)d_in[2];
    const float* Wk = (const float*)d_in[3];
    const float* Wv = (const float*)d_in[4];
    const float* Wr = (const float*)d_in[5];
    const int*   src = (const int*)d_in[6];
    const int*   dst = (const int*)d_in[7];
    float* out = (float*)d_out;
    float* Q   = (float*)d_ws;   // 50000*64 floats = 12.8 MB (same footprint as R1)

    init_out_kernel<<<3125, 256, 0, stream>>>((float4*)out);
    q_mfma_kernel<<<782, 256, 0, stream>>>(h, Wq, Q);
    edge_mfma_kernel<<<2500, 256, 0, stream>>>(h, e, Wk, Wv, Wr, Q, src, dst, out);
    finalize_kernel<<<3125, 256, 0, stream>>>((float4*)out);
}

// Round 3
// 526.715 us; speedup vs baseline: 2.1454x; 1.0549x over previous
//
#include <hip/hip_runtime.h>
#include <stdint.h>

// Problem constants
#define N_NODES 25000
#define N_EDGES 400000
// N=2, IN_DIM=64, HEADS=4, HEAD_DIM=16; feature rows = (node_or_edge*2+n)*64 floats

typedef __attribute__((ext_vector_type(8))) short short8;   // 8 bf16 = 4 VGPRs
typedef __attribute__((ext_vector_type(4))) short short4v;  // 8-byte LDS store
typedef __attribute__((ext_vector_type(4))) float f32x4;    // MFMA accum

#define MFMA16(a, b, c) __builtin_amdgcn_mfma_f32_16x16x32_bf16((a), (b), (c), 0, 0, 0)

// fp32 -> bf16 bits, round-to-nearest-even
__device__ __forceinline__ short bf16r(float x) {
    unsigned u = __float_as_uint(x);
    u += 0x7FFFu + ((u >> 16) & 1u);
    return (short)(u >> 16);
}

// B fragment for cols [colbase, colbase+16) of [64 x 64] row-major fp32 W.
// B layout: n = lane&15, k = (lane>>4)*8 + j (+32 per khalf). Validated R2.
__device__ __forceinline__ short8 load_bfrag(const float* __restrict__ W,
                                             int colbase, int lane, int khalf) {
    const int n = colbase + (lane & 15);
    const int k0 = khalf * 32 + ((lane >> 4) << 3);
    short8 f;
    #pragma unroll
    for (int j = 0; j < 8; ++j) f[j] = bf16r(W[(k0 + j) * 64 + n]);
    return f;
}

// A fragment from LDS tile (16 rows padded to 72 shorts = 144 B).
// A layout: m = lane&15, k = (lane>>4)*8 + j (+32 per khalf). Validated R2.
__device__ __forceinline__ short8 afrag(const short* S, int lane, int khalf) {
    return *(const short8*)&S[(lane & 15) * 72 + khalf * 32 + ((lane >> 4) << 3)];
}

// ---------- CSR build ----------
__global__ __launch_bounds__(256) void zero_counts_kernel(int* __restrict__ counts) {
    const int i = blockIdx.x * 256 + threadIdx.x;
    if (i < N_NODES) counts[i] = 0;
}

__global__ __launch_bounds__(256) void hist_kernel(const int* __restrict__ dst,
                                                   int* __restrict__ counts) {
    const int i = blockIdx.x * 256 + threadIdx.x;
    if (i < N_EDGES) atomicAdd(&counts[dst[i]], 1);
}

// single block, 256 threads; exclusive scan of 25000 counts -> offsets[25001], cursor
#define BPT 98   // 256*98 = 25088 >= 25000
__global__ __launch_bounds__(256) void scan_kernel(const int* __restrict__ counts,
                                                   int* __restrict__ offsets,
                                                   int* __restrict__ cursor) {
    __shared__ int part[256];
    const int t = threadIdx.x;
    const int base = t * BPT;
    int s = 0;
    for (int j = 0; j < BPT; ++j) {
        const int idx = base + j;
        if (idx < N_NODES) s += counts[idx];
    }
    part[t] = s;
    __syncthreads();
    for (int d = 1; d < 256; d <<= 1) {          // inclusive Hillis-Steele
        const int add = (t >= d) ? part[t - d] : 0;
        __syncthreads();
        part[t] += add;
        __syncthreads();
    }
    int run = (t > 0) ? part[t - 1] : 0;         // exclusive prefix
    for (int j = 0; j < BPT; ++j) {
        const int idx = base + j;
        if (idx < N_NODES) {
            offsets[idx] = run;
            cursor[idx]  = run;
            run += counts[idx];
        }
    }
    if (t == 255) offsets[N_NODES] = part[255];  // = N_EDGES
}

__global__ __launch_bounds__(256) void scatter_kernel(
    const int* __restrict__ src, const int* __restrict__ dst,
    int* __restrict__ cursor, int* __restrict__ perm, int* __restrict__ srcs) {
    const int i = blockIdx.x * 256 + threadIdx.x;
    if (i < N_EDGES) {
        const int d = dst[i];
        const int pos = atomicAdd(&cursor[d], 1);   // order within node irrelevant (max)
        perm[pos] = i;
        srcs[pos] = src[i];
    }
}

// ---------- weight fragment prep (1 block) ----------
// fw[(w*6 + f)*64 + lane], f = {K0,K1,V0,V1,R0,R1} for wave/head w
__global__ __launch_bounds__(256) void prep_frag_kernel(
    const float* __restrict__ Wk, const float* __restrict__ Wv,
    const float* __restrict__ Wr, short8* __restrict__ fw) {
    const int t = threadIdx.x;
    const int w = t >> 6, lane = t & 63, wcol = w << 4;
    fw[(w * 6 + 0) * 64 + lane] = load_bfrag(Wk, wcol, lane, 0);
    fw[(w * 6 + 1) * 64 + lane] = load_bfrag(Wk, wcol, lane, 1);
    fw[(w * 6 + 2) * 64 + lane] = load_bfrag(Wv, wcol, lane, 0);
    fw[(w * 6 + 3) * 64 + lane] = load_bfrag(Wv, wcol, lane, 1);
    fw[(w * 6 + 4) * 64 + lane] = load_bfrag(Wr, wcol, lane, 0);
    fw[(w * 6 + 5) * 64 + lane] = load_bfrag(Wr, wcol, lane, 1);
}

// ---------- Q = h @ W_Q (MFMA), 782 blocks x 64 rows ----------
__global__ __launch_bounds__(256) void q_mfma_kernel(
    const float* __restrict__ h, const float* __restrict__ Wq, float* __restrict__ Q)
{
    __shared__ short sH[64 * 72];
    const int t = threadIdx.x;
    const int lane = t & 63, w = t >> 6;
    const int wcol = w << 4;
    const int ln = lane & 15, lq = lane >> 4;
    const int base = blockIdx.x * 64;

    const short8 b0 = load_bfrag(Wq, wcol, lane, 0);
    const short8 b1 = load_bfrag(Wq, wcol, lane, 1);

    {
        const int r = t >> 2, c4 = (t & 3) << 4;
        int row = base + r; if (row > 49999) row = 49999;
        const float4* p = (const float4*)&h[row * 64 + c4];
        short tmp[16];
        #pragma unroll
        for (int i = 0; i < 4; ++i) {
            float4 x = p[i];
            tmp[4*i+0] = bf16r(x.x); tmp[4*i+1] = bf16r(x.y);
            tmp[4*i+2] = bf16r(x.z); tmp[4*i+3] = bf16r(x.w);
        }
        *(short8*)&sH[r * 72 + c4]     = *(short8*)&tmp[0];
        *(short8*)&sH[r * 72 + c4 + 8] = *(short8*)&tmp[8];
    }
    __syncthreads();

    #pragma unroll
    for (int m = 0; m < 4; ++m) {
        const short* Sm = &sH[(m << 4) * 72];
        short8 a0 = afrag(Sm, lane, 0);
        short8 a1 = afrag(Sm, lane, 1);
        f32x4 acc = {0.f, 0.f, 0.f, 0.f};
        acc = MFMA16(a0, b0, acc);
        acc = MFMA16(a1, b1, acc);
        #pragma unroll
        for (int reg = 0; reg < 4; ++reg) {
            const int row = base + (m << 4) + (lq << 2) + reg;
            if (row < 50000) Q[row * 64 + wcol + ln] = acc[reg];
        }
    }
}

// ---------- edge kernel: one block per dst node, single-writer, no atomics ----------
__global__ __launch_bounds__(256) void edge_csr_kernel(
    const float* __restrict__ h, const float* __restrict__ e,
    const float* __restrict__ Q, const int* __restrict__ srcs,
    const int* __restrict__ perm, const int* __restrict__ offsets,
    const short8* __restrict__ fw, float* __restrict__ out)
{
    const int v = blockIdx.x;
    const int t = threadIdx.x;
    const int off0 = offsets[v], off1 = offsets[v + 1];
    const int deg = off1 - off0;
    if (deg == 0) {                       // zero in-degree: DGL convention -> 0
        if (t < 128) out[(v << 7) + t] = 0.0f;
        return;
    }
    __shared__ short sD[16 * 72];
    __shared__ short sE[16 * 72];
    const int lane = t & 63, w = t >> 6;
    const int wcol = w << 4;
    const int ln = lane & 15, lq = lane >> 4;

    // resident weight fragments (6 coalesced b128 loads per wave)
    const short8 bK0 = fw[(w * 6 + 0) * 64 + lane];
    const short8 bK1 = fw[(w * 6 + 1) * 64 + lane];
    const short8 bV0 = fw[(w * 6 + 2) * 64 + lane];
    const short8 bV1 = fw[(w * 6 + 3) * 64 + lane];
    const short8 bR0 = fw[(w * 6 + 4) * 64 + lane];
    const short8 bR1 = fw[(w * 6 + 5) * 64 + lane];

    // Q[dst] values + per-(n,head) norms (block-invariant)
    const float q0 = Q[((v << 1) + 0) * 64 + wcol + ln];
    const float q1 = Q[((v << 1) + 1) * 64 + wcol + ln];
    float s0 = q0 * q0, s1 = q1 * q1;
    s0 += __shfl_xor(s0, 1); s1 += __shfl_xor(s1, 1);
    s0 += __shfl_xor(s0, 2); s1 += __shfl_xor(s1, 2);
    s0 += __shfl_xor(s0, 4); s1 += __shfl_xor(s1, 4);
    s0 += __shfl_xor(s0, 8); s1 += __shfl_xor(s1, 8);
    const float qn0 = sqrtf(s0), qn1 = sqrtf(s1);

    const float NEG_INF = __uint_as_float(0xFF800000u);
    float rm0 = NEG_INF, rm1 = NEG_INF;

    // staging role: row r (0..15) = (edge offset r>>1, n = r&1), 4-col group
    const int r = t >> 4;
    const int cq = (t & 15) << 2;
    const int n_r = r & 1;
    const int hd_base = (((v << 1) + n_r) << 6);

    const int nchunks = (deg + 7) >> 3;
    for (int c = 0; c < nchunks; ++c) {
        {   // ---- stage 8 edges x 2 n = 16 rows ----
            int eidx = off0 + (c << 3) + (r >> 1);
            const int ec = (eidx < off1 - 1) ? eidx : (off1 - 1);   // clamp (loads only)
            const int ed = perm[ec];
            const int s  = srcs[ec];
            const float4 xs = *(const float4*)&h[((((s  << 1) + n_r) << 6)) + cq];
            const float4 xd = *(const float4*)&h[hd_base + cq];
            const float4 xe = *(const float4*)&e[((((ed << 1) + n_r) << 6)) + cq];
            short4v d4, e4;
            d4[0] = bf16r(fmaxf(xs.x - xd.x, 0.f));
            d4[1] = bf16r(fmaxf(xs.y - xd.y, 0.f));
            d4[2] = bf16r(fmaxf(xs.z - xd.z, 0.f));
            d4[3] = bf16r(fmaxf(xs.w - xd.w, 0.f));
            e4[0] = bf16r(xe.x); e4[1] = bf16r(xe.y);
            e4[2] = bf16r(xe.z); e4[3] = bf16r(xe.w);
            *(short4v*)&sD[r * 72 + cq] = d4;
            *(short4v*)&sE[r * 72 + cq] = e4;
        }
        __syncthreads();

        short8 a0 = afrag(sD, lane, 0);
        short8 a1 = afrag(sD, lane, 1);
        short8 g0 = afrag(sE, lane, 0);
        short8 g1 = afrag(sE, lane, 1);
        f32x4 aK = {0.f, 0.f, 0.f, 0.f}, aV = aK, aR = aK;
        aK = MFMA16(a0, bK0, aK); aK = MFMA16(a1, bK1, aK);
        aV = MFMA16(a0, bV0, aV); aV = MFMA16(a1, bV1, aV);
        aR = MFMA16(g0, bR0, aR); aR = MFMA16(g1, bR1, aR);

        #pragma unroll
        for (int reg = 0; reg < 4; ++reg) {
            const int rl = (lq << 2) + reg;               // C row = quad*4+reg
            const int eloc = rl >> 1;
            const bool valid = ((c << 3) + eloc) < deg;
            const float kk = aK[reg];
            float sk = kk * kk;                           // ||k|| over 16 head cols
            sk += __shfl_xor(sk, 1);
            sk += __shfl_xor(sk, 2);
            sk += __shfl_xor(sk, 4);
            sk += __shfl_xor(sk, 8);
            const int n2 = rl & 1;
            const float scale = sqrtf(sk) * (n2 ? qn1 : qn0) + 1e-6f;
            const float qv = n2 ? q1 : q0;
            float msg = (qv * kk * scale + aR[reg]) * aV[reg];
            msg = valid ? msg : NEG_INF;
            if (n2) rm1 = fmaxf(rm1, msg); else rm0 = fmaxf(rm0, msg);
        }
        __syncthreads();   // protect sD/sE before next chunk's staging
    }

    // max across quads (each quad covered a disjoint pair of edges per chunk)
    rm0 = fmaxf(rm0, __shfl_xor(rm0, 16));
    rm0 = fmaxf(rm0, __shfl_xor(rm0, 32));
    rm1 = fmaxf(rm1, __shfl_xor(rm1, 16));
    rm1 = fmaxf(rm1, __shfl_xor(rm1, 32));
    if (lq == 0) out[(v << 7) + wcol + ln]      = rm0;
    if (lq == 1) out[(v << 7) + 64 + wcol + ln] = rm1;
}

extern "C" void kernel_launch(void* const* d_in, const int* in_sizes, int n_in,
                              void* d_out, int out_size, void* d_ws, size_t ws_size,
                              hipStream_t stream) {
    const float* h  = (const float*)d_in[0];
    const float* e  = (const float*)d_in[1];
    const float* Wq = (const float*)d_in[2];
    const float* Wk = (const float*)d_in[3];
    const float* Wv = (const float*)d_in[4];
    const float* Wr = (const float*)d_in[5];
    const int*   src = (const int*)d_in[6];
    const int*   dst = (const int*)d_in[7];
    float* out = (float*)d_out;

    // workspace layout (ints/floats are 4B):  total ~16.3 MB
    float* Q       = (float*)d_ws;                    // 3,200,000 floats
    int*   counts  = (int*)d_ws + 3200000;            // 25,000
    int*   offsets = (int*)d_ws + 3225000;            // 25,001
    int*   cursor  = (int*)d_ws + 3250008;            // 25,000
    int*   perm    = (int*)d_ws + 3275008;            // 400,000
    int*   srcs    = (int*)d_ws + 3675008;            // 400,000
    short8* fw     = (short8*)((int*)d_ws + 4075008); // 1536 x 16B (16B-aligned)

    zero_counts_kernel<<<98, 256, 0, stream>>>(counts);
    hist_kernel<<<1563, 256, 0, stream>>>(dst, counts);
    scan_kernel<<<1, 256, 0, stream>>>(counts, offsets, cursor);
    scatter_kernel<<<1563, 256, 0, stream>>>(src, dst, cursor, perm, srcs);
    prep_frag_kernel<<<1, 256, 0, stream>>>(Wk, Wv, Wr, fw);
    q_mfma_kernel<<<782, 256, 0, stream>>>(h, Wq, Q);
    edge_csr_kernel<<<25000, 256, 0, stream>>>(h, e, Q, srcs, perm, offsets, fw, out);
}

// Round 4
// 513.383 us; speedup vs baseline: 2.2011x; 1.0260x over previous
//
#include <hip/hip_runtime.h>
#include <stdint.h>

// Problem constants
#define N_NODES 25000
#define N_EDGES 400000
// N=2, IN_DIM=64, HEADS=4, HEAD_DIM=16; feature rows = (idx*2+n)*64 floats

typedef __attribute__((ext_vector_type(8))) short short8;   // 8 bf16 = 4 VGPRs
typedef __attribute__((ext_vector_type(4))) float f32x4;    // MFMA accum

#define MFMA16(a, b, c) __builtin_amdgcn_mfma_f32_16x16x32_bf16((a), (b), (c), 0, 0, 0)

// fp32 -> bf16, round-to-nearest-even (weights / q path)
__device__ __forceinline__ short bf16r(float x) {
    unsigned u = __float_as_uint(x);
    u += 0x7FFFu + ((u >> 16) & 1u);
    return (short)(u >> 16);
}
// fp32 -> bf16, round-half-up (hot edge path: 2 VALU ops; bias negligible vs threshold)
__device__ __forceinline__ short bfr(float x) {
    return (short)((__float_as_uint(x) + 0x8000u) >> 16);
}

// Sum over each 16-lane group via DPP butterfly (pure VALU, no DS traffic).
#define DPP_ADD(x, ctrl) \
    ((x) + __int_as_float(__builtin_amdgcn_update_dpp(0, __float_as_int(x), (ctrl), 0xF, 0xF, true)))
__device__ __forceinline__ float red16(float x) {
    x = DPP_ADD(x, 0xB1);    // quad_perm [1,0,3,2]  (xor 1)
    x = DPP_ADD(x, 0x4E);    // quad_perm [2,3,0,1]  (xor 2)
    x = DPP_ADD(x, 0x141);   // row_half_mirror      (8-group)
    x = DPP_ADD(x, 0x140);   // row_mirror           (16-group)
    return x;
}

// B fragment for cols [colbase, colbase+16) of [64 x 64] row-major fp32 W.
// B layout: n = lane&15, k = (lane>>4)*8 + j (+32 per khalf). Validated R2/R3.
__device__ __forceinline__ short8 load_bfrag(const float* __restrict__ W,
                                             int colbase, int lane, int khalf) {
    const int n = colbase + (lane & 15);
    const int k0 = khalf * 32 + ((lane >> 4) << 3);
    short8 f;
    #pragma unroll
    for (int j = 0; j < 8; ++j) f[j] = bf16r(W[(k0 + j) * 64 + n]);
    return f;
}

// A fragment from LDS tile (16 rows padded to 72 shorts = 144 B). Validated R2/R3.
__device__ __forceinline__ short8 afrag(const short* S, int lane, int khalf) {
    return *(const short8*)&S[(lane & 15) * 72 + khalf * 32 + ((lane >> 4) << 3)];
}

// ---------- CSR build ----------
__global__ __launch_bounds__(256) void zero_counts_kernel(int* __restrict__ counts) {
    const int i = blockIdx.x * 256 + threadIdx.x;
    if (i < N_NODES) counts[i] = 0;
}

__global__ __launch_bounds__(256) void hist_kernel(const int* __restrict__ dst,
                                                   int* __restrict__ counts) {
    const int i = blockIdx.x * 256 + threadIdx.x;
    if (i < N_EDGES) atomicAdd(&counts[dst[i]], 1);
}

#define BPT 98   // 256*98 = 25088 >= 25000
__global__ __launch_bounds__(256) void scan_kernel(const int* __restrict__ counts,
                                                   int* __restrict__ offsets,
                                                   int* __restrict__ cursor) {
    __shared__ int part[256];
    const int t = threadIdx.x;
    const int base = t * BPT;
    int s = 0;
    for (int j = 0; j < BPT; ++j) {
        const int idx = base + j;
        if (idx < N_NODES) s += counts[idx];
    }
    part[t] = s;
    __syncthreads();
    for (int d = 1; d < 256; d <<= 1) {
        const int add = (t >= d) ? part[t - d] : 0;
        __syncthreads();
        part[t] += add;
        __syncthreads();
    }
    int run = (t > 0) ? part[t - 1] : 0;
    for (int j = 0; j < BPT; ++j) {
        const int idx = base + j;
        if (idx < N_NODES) {
            offsets[idx] = run;
            cursor[idx]  = run;
            run += counts[idx];
        }
    }
    if (t == 255) offsets[N_NODES] = part[255];
}

__global__ __launch_bounds__(256) void scatter_kernel(
    const int* __restrict__ src, const int* __restrict__ dst,
    int* __restrict__ cursor, int* __restrict__ perm, int* __restrict__ srcs) {
    const int i = blockIdx.x * 256 + threadIdx.x;
    if (i < N_EDGES) {
        const int d = dst[i];
        const int pos = atomicAdd(&cursor[d], 1);
        perm[pos] = i;
        srcs[pos] = src[i];
    }
}

// ---------- Q = h @ W_Q (MFMA) + fused weight-fragment prep (block 0) ----------
__global__ __launch_bounds__(256) void q_mfma_kernel(
    const float* __restrict__ h, const float* __restrict__ Wq,
    const float* __restrict__ Wk, const float* __restrict__ Wv,
    const float* __restrict__ Wr, float* __restrict__ Q, short8* __restrict__ fw)
{
    __shared__ short sH[64 * 72];
    const int t = threadIdx.x;
    const int lane = t & 63, w = t >> 6;
    const int wcol = w << 4;
    const int ln = lane & 15, lq = lane >> 4;
    const int base = blockIdx.x * 64;

    const short8 b0 = load_bfrag(Wq, wcol, lane, 0);
    const short8 b1 = load_bfrag(Wq, wcol, lane, 1);

    {
        const int r = t >> 2, c4 = (t & 3) << 4;
        int row = base + r; if (row > 49999) row = 49999;
        const float4* p = (const float4*)&h[row * 64 + c4];
        short tmp[16];
        #pragma unroll
        for (int i = 0; i < 4; ++i) {
            float4 x = p[i];
            tmp[4*i+0] = bf16r(x.x); tmp[4*i+1] = bf16r(x.y);
            tmp[4*i+2] = bf16r(x.z); tmp[4*i+3] = bf16r(x.w);
        }
        *(short8*)&sH[r * 72 + c4]     = *(short8*)&tmp[0];
        *(short8*)&sH[r * 72 + c4 + 8] = *(short8*)&tmp[8];
    }
    __syncthreads();

    #pragma unroll
    for (int m = 0; m < 4; ++m) {
        const short* Sm = &sH[(m << 4) * 72];
        short8 a0 = afrag(Sm, lane, 0);
        short8 a1 = afrag(Sm, lane, 1);
        f32x4 acc = {0.f, 0.f, 0.f, 0.f};
        acc = MFMA16(a0, b0, acc);
        acc = MFMA16(a1, b1, acc);
        #pragma unroll
        for (int reg = 0; reg < 4; ++reg) {
            const int row = base + (m << 4) + (lq << 2) + reg;
            if (row < 50000) Q[row * 64 + wcol + ln] = acc[reg];
        }
    }

    if (blockIdx.x == 0) {   // weight fragments for the edge kernel
        fw[(w * 6 + 0) * 64 + lane] = load_bfrag(Wk, wcol, lane, 0);
        fw[(w * 6 + 1) * 64 + lane] = load_bfrag(Wk, wcol, lane, 1);
        fw[(w * 6 + 2) * 64 + lane] = load_bfrag(Wv, wcol, lane, 0);
        fw[(w * 6 + 3) * 64 + lane] = load_bfrag(Wv, wcol, lane, 1);
        fw[(w * 6 + 4) * 64 + lane] = load_bfrag(Wr, wcol, lane, 0);
        fw[(w * 6 + 5) * 64 + lane] = load_bfrag(Wr, wcol, lane, 1);
    }
}

// ---------- edge kernel: one WAVE per dst node, barrier-free ----------
// Wave stages its node's 8-edge (16-row) chunk into a private LDS slab,
// wave-synchronously (same-wave DS ops are in-order; wave_barrier pins compiler
// ordering). All 4 heads per wave: 24 resident B-frags (96 VGPRs).
__global__ __launch_bounds__(256, 2) void edge_wave_kernel(
    const float* __restrict__ h, const float* __restrict__ e,
    const float* __restrict__ Q, const int* __restrict__ srcs,
    const int* __restrict__ perm, const int* __restrict__ offsets,
    const short8* __restrict__ fw, float* __restrict__ out)
{
    __shared__ short sAll[4][2304];          // per-wave: D[0..1151], E[1152..2303]
    const int t = threadIdx.x;
    const int lane = t & 63, w = t >> 6;
    const int v = (blockIdx.x << 2) + w;     // 6250*4 = 25000 exactly
    short* SD = &sAll[w][0];
    short* SE = &sAll[w][1152];

    const int off0 = offsets[v];
    const int off1 = offsets[v + 1];
    const int deg  = off1 - off0;

    if (deg == 0) {                          // zero in-degree -> 0 (DGL convention)
        out[(v << 7) + lane]      = 0.0f;
        out[(v << 7) + 64 + lane] = 0.0f;
        return;                              // whole-wave exit; no block barriers exist
    }

    const int ln = lane & 15, lq = lane >> 4;

    // all-head resident weight fragments (24 x b128, L2-hot)
    short8 bK0[4], bK1[4], bV0[4], bV1[4], bR0[4], bR1[4];
    #pragma unroll
    for (int hd = 0; hd < 4; ++hd) {
        bK0[hd] = fw[(hd * 6 + 0) * 64 + lane];
        bK1[hd] = fw[(hd * 6 + 1) * 64 + lane];
        bV0[hd] = fw[(hd * 6 + 2) * 64 + lane];
        bV1[hd] = fw[(hd * 6 + 3) * 64 + lane];
        bR0[hd] = fw[(hd * 6 + 4) * 64 + lane];
        bR1[hd] = fw[(hd * 6 + 5) * 64 + lane];
    }

    // Q rows + per-(n,head) norms (block... wave-invariant)
    float q0[4], q1[4], qn0[4], qn1[4];
    #pragma unroll
    for (int hd = 0; hd < 4; ++hd) {
        q0[hd] = Q[(v << 7) + (hd << 4) + ln];
        q1[hd] = Q[(v << 7) + 64 + (hd << 4) + ln];
        qn0[hd] = sqrtf(red16(q0[hd] * q0[hd]));
        qn1[hd] = sqrtf(red16(q1[hd] * q1[hd]));
    }

    // staging role: lane -> A-row r = lane>>2 (edge r>>1, n = r&1), cols cq..cq+15
    const int r = lane >> 2;
    const int cq = (lane & 3) << 4;
    const int n_r = r & 1;

    // hoisted dst-row fragment (node-invariant across chunks)
    float4 xd[4];
    {
        const float4* pd = (const float4*)&h[(((v << 1) + n_r) << 6) + cq];
        xd[0] = pd[0]; xd[1] = pd[1]; xd[2] = pd[2]; xd[3] = pd[3];
    }

    const float NEG_INF = __uint_as_float(0xFF800000u);
    float rm0[4] = {NEG_INF, NEG_INF, NEG_INF, NEG_INF};
    float rm1[4] = {NEG_INF, NEG_INF, NEG_INF, NEG_INF};

    const int nch = (deg + 7) >> 3;
    for (int c = 0; c < nch; ++c) {
        int eidx = off0 + (c << 3) + (r >> 1);
        if (eidx > off1 - 1) eidx = off1 - 1;           // clamp (loads only; masked later)
        const int ed = perm[eidx];
        const int s  = srcs[eidx];
        const float4* ps = (const float4*)&h[(((s  << 1) + n_r) << 6) + cq];
        const float4* pe = (const float4*)&e[(((ed << 1) + n_r) << 6) + cq];

        short tmd[16], tme[16];
        #pragma unroll
        for (int i = 0; i < 4; ++i) {
            const float4 xs = ps[i], xe = pe[i];
            tmd[4*i+0] = bfr(fmaxf(xs.x - xd[i].x, 0.f));
            tmd[4*i+1] = bfr(fmaxf(xs.y - xd[i].y, 0.f));
            tmd[4*i+2] = bfr(fmaxf(xs.z - xd[i].z, 0.f));
            tmd[4*i+3] = bfr(fmaxf(xs.w - xd[i].w, 0.f));
            tme[4*i+0] = bfr(xe.x); tme[4*i+1] = bfr(xe.y);
            tme[4*i+2] = bfr(xe.z); tme[4*i+3] = bfr(xe.w);
        }
        *(short8*)&SD[r * 72 + cq]     = *(short8*)&tmd[0];
        *(short8*)&SD[r * 72 + cq + 8] = *(short8*)&tmd[8];
        *(short8*)&SE[r * 72 + cq]     = *(short8*)&tme[0];
        *(short8*)&SE[r * 72 + cq + 8] = *(short8*)&tme[8];

        __builtin_amdgcn_wave_barrier();   // order: writes above before reads below

        const short8 a0 = afrag(SD, lane, 0);
        const short8 a1 = afrag(SD, lane, 1);
        const short8 g0 = afrag(SE, lane, 0);
        const short8 g1 = afrag(SE, lane, 1);

        #pragma unroll
        for (int hd = 0; hd < 4; ++hd) {
            f32x4 aK = {0.f, 0.f, 0.f, 0.f}, aV = aK, aR = aK;
            aK = MFMA16(a0, bK0[hd], aK); aK = MFMA16(a1, bK1[hd], aK);
            aV = MFMA16(a0, bV0[hd], aV); aV = MFMA16(a1, bV1[hd], aV);
            aR = MFMA16(g0, bR0[hd], aR); aR = MFMA16(g1, bR1[hd], aR);

            #pragma unroll
            for (int reg = 0; reg < 4; ++reg) {
                const int rl   = (lq << 2) + reg;       // C row = quad*4+reg
                const int eloc = rl >> 1;
                const int n2   = reg & 1;               // == rl&1
                const bool valid = ((c << 3) + eloc) < deg;
                const float kk = aK[reg];
                const float sk = red16(kk * kk);        // ||k||^2 over head's 16 cols
                const float scale = sqrtf(sk) * (n2 ? qn1[hd] : qn0[hd]) + 1e-6f;
                const float qv = n2 ? q1[hd] : q0[hd];
                float msg = (qv * kk * scale + aR[reg]) * aV[reg];
                msg = valid ? msg : NEG_INF;
                if (n2) rm1[hd] = fmaxf(rm1[hd], msg);
                else    rm0[hd] = fmaxf(rm0[hd], msg);
            }
        }
        __builtin_amdgcn_wave_barrier();   // order: reads above before next iter's writes
    }

    // max across quads (disjoint edges per quad), then coalesced store (col = lane)
    #pragma unroll
    for (int hd = 0; hd < 4; ++hd) {
        rm0[hd] = fmaxf(rm0[hd], __shfl_xor(rm0[hd], 16));
        rm0[hd] = fmaxf(rm0[hd], __shfl_xor(rm0[hd], 32));
        rm1[hd] = fmaxf(rm1[hd], __shfl_xor(rm1[hd], 16));
        rm1[hd] = fmaxf(rm1[hd], __shfl_xor(rm1[hd], 32));
    }
    const float o0 = (lq == 0) ? rm0[0] : (lq == 1) ? rm0[1] : (lq == 2) ? rm0[2] : rm0[3];
    const float o1 = (lq == 0) ? rm1[0] : (lq == 1) ? rm1[1] : (lq == 2) ? rm1[2] : rm1[3];
    out[(v << 7) + lane]      = o0;
    out[(v << 7) + 64 + lane] = o1;
}

extern "C" void kernel_launch(void* const* d_in, const int* in_sizes, int n_in,
                              void* d_out, int out_size, void* d_ws, size_t ws_size,
                              hipStream_t stream) {
    const float* h  = (const float*)d_in[0];
    const float* e  = (const float*)d_in[1];
    const float* Wq = (const float*)d_in[2];
    const float* Wk = (const float*)d_in[3];
    const float* Wv = (const float*)d_in[4];
    const float* Wr = (const float*)d_in[5];
    const int*   src = (const int*)d_in[6];
    const int*   dst = (const int*)d_in[7];
    float* out = (float*)d_out;

    // workspace layout (4B units), ~16.3 MB total
    float* Q       = (float*)d_ws;                    // 3,200,000
    int*   counts  = (int*)d_ws + 3200000;            // 25,000
    int*   offsets = (int*)d_ws + 3225000;            // 25,001
    int*   cursor  = (int*)d_ws + 3250008;            // 25,000
    int*   perm    = (int*)d_ws + 3275008;            // 400,000
    int*   srcs    = (int*)d_ws + 3675008;            // 400,000
    short8* fw     = (short8*)((int*)d_ws + 4075008); // 1536 x 16B

    zero_counts_kernel<<<98, 256, 0, stream>>>(counts);
    hist_kernel<<<1563, 256, 0, stream>>>(dst, counts);
    scan_kernel<<<1, 256, 0, stream>>>(counts, offsets, cursor);
    scatter_kernel<<<1563, 256, 0, stream>>>(src, dst, cursor, perm, srcs);
    q_mfma_kernel<<<782, 256, 0, stream>>>(h, Wq, Wk, Wv, Wr, Q, fw);
    edge_wave_kernel<<<6250, 256, 0, stream>>>(h, e, Q, srcs, perm, offsets, fw, out);
}